// Round 14
// baseline (65.883 us; speedup 1.0000x reference)
//
#include <hip/hip_runtime.h>

#define W_ 8192
#define NBATCH 2048
#define NT 256
#define NWAVE 4
#define SEGW 2048   // cols per wave
#define HALO 192
#define RWN (SEGW + 2*HALO)   // 2432 staged elems per wave
#define CCH 256
#define NCHW 8      // chunks per wave
#define IRW 272     // f16 units per wave irow

typedef unsigned short u16_t;
typedef _Float16 h2v __attribute__((ext_vector_type(2)));

__device__ __forceinline__ u16_t f2h(float x){ _Float16 h=(_Float16)x; return __builtin_bit_cast(u16_t,h); }
__device__ __forceinline__ float h2f(u16_t u){ return (float)__builtin_bit_cast(_Float16,u); }
__device__ __forceinline__ unsigned pk2(float a,float b){ return (unsigned)f2h(a)|((unsigned)f2h(b)<<16); }
__device__ __forceinline__ float dot2u(unsigned a,unsigned b,float c){
#if __has_builtin(__builtin_amdgcn_fdot2)
  return __builtin_amdgcn_fdot2(__builtin_bit_cast(h2v,a),__builtin_bit_cast(h2v,b),c,false);
#else
  h2v ha=__builtin_bit_cast(h2v,a), hb=__builtin_bit_cast(h2v,b);
  return c+(float)ha[0]*(float)hb[0]+(float)ha[1]*(float)hb[1];
#endif
}
__device__ __forceinline__ unsigned pkrtz(float a,float b){
#if __has_builtin(__builtin_amdgcn_cvt_pkrtz)
  return __builtin_bit_cast(unsigned, __builtin_amdgcn_cvt_pkrtz(a,b));
#else
  return pk2(a,b);
#endif
}
__device__ __forceinline__ unsigned alignb(unsigned hi, unsigned lo){
#if __has_builtin(__builtin_amdgcn_alignbit)
  return __builtin_amdgcn_alignbit(hi, lo, 16);
#else
  return (lo >> 16) | (hi << 16);
#endif
}
__device__ __forceinline__ float softplusf(float x){ return fmaxf(x,0.f)+log1pf(expf(-fabsf(x))); }
__device__ __forceinline__ unsigned rflv(unsigned v){
  return (unsigned)__builtin_amdgcn_readfirstlane((int)v);
}
__device__ __forceinline__ float rflvf(float v){
  return __builtin_bit_cast(float, __builtin_amdgcn_readfirstlane(__builtin_bit_cast(int, v)));
}

// ---------------- K0: table pack + per-row params ----------------
__global__ __launch_bounds__(256, 2)
void doas_prep(const float* __restrict__ absn, const float* __restrict__ cbn,
               const float* __restrict__ ray, const int* __restrict__ iid,
               const float* __restrict__ nuis, const float* __restrict__ emb,
               const float* __restrict__ w1, const float* __restrict__ b1,
               const float* __restrict__ w2, const float* __restrict__ b2,
               unsigned* __restrict__ Tp, float* __restrict__ params){
  const int tid = threadIdx.x;
  const int b = blockIdx.x;
  __shared__ float hS[4][64];
  __shared__ float pS[4][8];

  if (b < 32){
    const int w = b*256 + tid;
    #pragma unroll
    for (int q=0;q<4;++q) Tp[q*W_+w]     = pk2(absn[(2*q)*W_+w], absn[(2*q+1)*W_+w]);
    #pragma unroll
    for (int q=0;q<4;++q) Tp[(4+q)*W_+w] = pk2(cbn[(2*q)*W_+w],  cbn[(2*q+1)*W_+w]);
    Tp[8*W_+w] = pk2(cbn[8*W_+w], ray[w]);
  }

  {
    const int rl = tid >> 6, j = tid & 63;
    const int r = b*4 + rl;
    const int id = iid[r];
    float acc = b1[j];
    const float* nrow = nuis + (size_t)r * 8;
    #pragma unroll
    for (int i = 0; i < 8; ++i) acc = fmaf(nrow[i], w1[i*64 + j], acc);
    const float* erow = emb + (size_t)id * 128;
    for (int i = 0; i < 128; ++i) acc = fmaf(erow[i], w1[(8+i)*64 + j], acc);
    hS[rl][j] = 0.5f * acc * (1.0f + erff(acc * 0.70710678118654752f));
  }
  __syncthreads();
  if (tid < 4*7){
    const int rl = tid / 7, k = tid % 7;
    float p = b2[k];
    for (int j = 0; j < 64; ++j) p = fmaf(hS[rl][j], w2[j*7+k], p);
    pS[rl][k] = p;
  }
  __syncthreads();
  if (tid < 4){
    const int rl = tid;
    const int r = b*4 + rl;
    float p0=pS[rl][0], p1=pS[rl][1], p2=pS[rl][2], p3=pS[rl][3],
          p4=pS[rl][4], p5=pS[rl][5], p6=pS[rl][6];
    float gainv = softplusf(p0) + 0.001f;
    float offv  = p1;
    float woffv = 0.05f * tanhf(p2);
    float wscv  = 1.0f + 0.005f * tanhf(p3);
    float lsf   = fminf(fmaxf(softplusf(p4) + 0.001f, 0.2f), 5.0f);
    float strv  = fminf(fmaxf((1.0f/(1.0f+expf(-p5))) * 0.05f, 0.0f), 0.2f);
    float nlin  = fminf(fmaxf(0.02f * tanhf(p6), -0.04f), 0.04f);
    float iw = 1.0f/(lsf + 1e-6f);
    float ks[15]; float ksum = 0.f;
    #pragma unroll
    for (int k2=0;k2<15;++k2){ float pp=(float)(k2-7)*iw; float e=expf(-0.5f*pp*pp); ks[k2]=e; ksum+=e; }
    float inv = 1.0f/ksum;
    float* pr = params + (size_t)r*16;
    unsigned* pu = (unsigned*)pr;
    #pragma unroll
    for (int i=0;i<7;++i) pu[i] = pk2(ks[2*i]*inv, ks[2*i+1]*inv);
    pu[7] = pk2(ks[14]*inv, 0.0f);   // k14lo
    pr[9]  = wscv;
    pr[10] = (300.0f*(wscv - 1.0f) + woffv) * (8191.0f/100.0f);  // posoff
    pr[11] = gainv; pr[12] = offv; pr[13] = nlin; pr[14] = strv;
    pr[15] = 0.f;
  }
}

// interp one 270-sample chunk (136 pairs) from wave-private LDS into wave irow
template<bool CLO, bool CHI>
__device__ __forceinline__ void interp_chunk(int cbase, int base, int l,
                                             const unsigned* __restrict__ rWU,
                                             unsigned* __restrict__ irowU,
                                             float wscale, float posoff){
  #pragma unroll
  for (int it=0; it<3; ++it){
    const int pi = it*64 + l;
    if (pi < 136){
      float v2[2];
      #pragma unroll
      for (int u=0;u<2;++u){
        int j = cbase + 2*pi + u;
        if (CLO) j = max(j, 0);
        if (CHI) j = min(j, W_-1);
        float pos = fmaf((float)j, wscale, posoff);
        if (CLO) pos = fmaxf(pos, 0.0f);
        if (CHI) pos = fminf(pos, 8191.0f);
        int i0 = (int)pos;
        if (CHI) i0 = min(i0, W_-2);
        const float fr = pos - (float)i0;
        const int li = i0 - base;           // local staged index (base even)
        const int m = li >> 1;
        const unsigned u0 = rWU[m];
        const unsigned u1 = rWU[m+1];
        const unsigned hu0 = u0 >> 16;
        const bool odd = (li & 1);
        const unsigned ua = odd ? hu0 : u0;
        const unsigned ub = odd ? u1  : hu0;
        const float d0 = h2f((u16_t)ua);
        const float d1 = h2f((u16_t)ub);
        v2[u] = fmaf(fr, d1-d0, d0);
      }
      irowU[pi] = pkrtz(v2[0], v2[1]);
    }
  }
}

// ---------------- K1: fused, wave-autonomous (1 row/block, 4 waves x 2048 cols) ----------------
__global__ __launch_bounds__(NT, 2)
void doas_main6(const unsigned* __restrict__ Tp, const float* __restrict__ gas,
                const float* __restrict__ air, const float* __restrict__ params,
                float* __restrict__ out){
  __shared__ u16_t rowW[NWAVE][RWN + 8];   // wave-private staged diff (f16) ~19.5 KB
  __shared__ u16_t irowS[NWAVE][IRW];      // 2.2 KB
  __shared__ float wsumS[NWAVE];

  const int tid = threadIdx.x;
  const int row = blockIdx.x;
  const int wid = tid >> 6, l = tid & 63;
  const int segbase = wid * SEGW;
  const int base = segbase - HALO;         // even

  // ---- diff coefficients (row-uniform) -> SGPRs ----
  unsigned csg[9];
  {
    const float am = air[row];
    const float* gfp = gas + (size_t)row * 8;
    #pragma unroll
    for (int q=0;q<4;++q) csg[q]   = rflv(pk2(gfp[2*q]*am, gfp[2*q+1]*am));
    #pragma unroll
    for (int q=0;q<4;++q) csg[4+q] = rflv(pk2(gfp[2*q],    gfp[2*q+1]));
    csg[8] = rflv(pk2(1.0f, am));
  }

  // ---- per-row params (wave-uniform) ----
  const float* pr = params + (size_t)row * 16;
  const unsigned* pu = (const unsigned*)pr;
  unsigned kwp[7];
  #pragma unroll
  for (int i=0;i<7;++i) kwp[i] = rflv(pu[i]);
  const unsigned k14lo = rflv(pu[7]);
  const float wscale = rflvf(pr[9]),  posoff = rflvf(pr[10]);
  const float gainv  = rflvf(pr[11]), offv   = rflvf(pr[12]);
  const float nlin   = rflvf(pr[13]), strv   = rflvf(pr[14]);

  // ---- wave-private stage: diff for [base, base+RWN) : 1216 pairs = 19 iters ----
  unsigned* rWU = (unsigned*)&rowW[wid][0];
  #pragma unroll
  for (int it=0; it<19; ++it){
    const int idx = it*64 + l;               // pair index 0..1215
    const int e0 = base + 2*idx;
    const int eL = min(max(e0, 0), W_-2);
    float a0=0.f, a1=0.f;
    #pragma unroll
    for (int q=0;q<9;++q){
      uint2 d = *(const uint2*)(Tp + q*W_ + eL);
      a0 = dot2u(d.x, csg[q], a0);
      a1 = dot2u(d.y, csg[q], a1);
    }
    rWU[idx] = pkrtz(a0, a1);
  }
  __builtin_amdgcn_wave_barrier();

  u16_t* irow = &irowS[wid][0];
  unsigned* irowU = (unsigned*)irow;

  float accsum = 0.f;
  unsigned nlp[NCHW][2];

  #pragma unroll
  for (int c = 0; c < NCHW; ++c) {
    const int cs = segbase + c*CCH;
    const int cbase = cs - 8;
    if (wid == 0 && c == 0)
      interp_chunk<true,false>(cbase, base, l, rWU, irowU, wscale, posoff);
    else if (wid == NWAVE-1 && c == NCHW-1)
      interp_chunk<false,true>(cbase, base, l, rWU, irowU, wscale, posoff);
    else
      interp_chunk<false,false>(cbase, base, l, rWU, irowU, wscale, posoff);
    __builtin_amdgcn_wave_barrier();
    // conv(15) + exp + post + nl ; lane owns 4 outputs at cs + 4l
    {
      const uint2* p2 = (const uint2*)irowU + l;
      const uint2 A = p2[0], B = p2[1], C = p2[2], D = p2[3], E = p2[4];
      unsigned q[10] = {A.x,A.y, B.x,B.y, C.x,C.y, D.x,D.y, E.x,E.y};
      unsigned sh[9];
      #pragma unroll
      for (int m=0;m<9;++m) sh[m] = alignb(q[m+1], q[m]);
      float nlv[4];
      #pragma unroll
      for (int t=0;t<4;++t){
        float cv = 0.f;
        if ((t & 1) == 0){
          const int b0 = t >> 1;
          #pragma unroll
          for (int i=0;i<7;++i) cv = dot2u(sh[b0+i], kwp[i], cv);
          cv = dot2u(sh[b0+7], k14lo, cv);
        } else {
          const int b0 = (t+1) >> 1;
          #pragma unroll
          for (int i=0;i<7;++i) cv = dot2u(q[b0+i], kwp[i], cv);
          cv = dot2u(q[b0+7], k14lo, cv);
        }
        const float counts = __expf(-cv);
        const float post = fmaf(gainv, counts, offv);
        const float v = fmaf(nlin*post, post, post);
        accsum += v;
        nlv[t] = v;
      }
      nlp[c][0] = pkrtz(nlv[0], nlv[1]);
      nlp[c][1] = pkrtz(nlv[2], nlv[3]);
    }
    __builtin_amdgcn_wave_barrier();
  }

  // ---- row mean (only block-wide sync) ----
  float s = accsum;
  #pragma unroll
  for (int off2 = 32; off2 >= 1; off2 >>= 1) s += __shfl_down(s, off2);
  if (l == 0) wsumS[wid] = s;
  __syncthreads();
  const float meanv = (wsumS[0]+wsumS[1]+wsumS[2]+wsumS[3]) * (1.0f/8192.0f);

  // ---- final write ----
  {
    const float aa = 1.0f - strv;
    const float bb = strv * meanv;
    float* orow = out + (size_t)row * W_;
    #pragma unroll
    for (int c = 0; c < NCHW; ++c) {
      const unsigned u0 = nlp[c][0], u1 = nlp[c][1];
      float4 o0;
      o0.x = fmaf(aa, h2f((u16_t)(u0 & 0xffffu)), bb);
      o0.y = fmaf(aa, h2f((u16_t)(u0 >> 16)),     bb);
      o0.z = fmaf(aa, h2f((u16_t)(u1 & 0xffffu)), bb);
      o0.w = fmaf(aa, h2f((u16_t)(u1 >> 16)),     bb);
      *(float4*)(orow + segbase + c*CCH + 4*l) = o0;
    }
  }
}

// ---------------- fallback: monolithic kernel reading raw tables ----------------
__global__ __launch_bounds__(256, 2)
void doas_mono(const float* __restrict__ gas, const int* __restrict__ iid,
               const float* __restrict__ nuis, const float* __restrict__ air,
               const float* __restrict__ absn, const float* __restrict__ cbn,
               const float* __restrict__ ray, const float* __restrict__ emb,
               const float* __restrict__ w1, const float* __restrict__ b1,
               const float* __restrict__ w2, const float* __restrict__ b2,
               float* __restrict__ out)
{
  __shared__ u16_t ringS[4][2048];
  __shared__ u16_t irowS2[4][544];
  __shared__ float hS[64];
  __shared__ float pS[8];
  __shared__ float scalS[52];
  __shared__ float wsumS[4];

  const int tid = threadIdx.x;
  const int row = blockIdx.x;

  if (tid < 64) {
    const int j = tid;
    const int id = iid[row];
    float acc = b1[j];
    const float* nrow = nuis + (size_t)row * 8;
    #pragma unroll
    for (int i = 0; i < 8; ++i) acc = fmaf(nrow[i], w1[i*64 + j], acc);
    const float* erow = emb + (size_t)id * 128;
    for (int i = 0; i < 128; ++i) acc = fmaf(erow[i], w1[(8+i)*64 + j], acc);
    hS[j] = 0.5f * acc * (1.0f + erff(acc * 0.70710678118654752f));
  }
  __syncthreads();
  if (tid < 7) {
    float p = b2[tid];
    for (int j = 0; j < 64; ++j) p = fmaf(hS[j], w2[j*7+tid], p);
    pS[tid] = p;
  }
  __syncthreads();
  if (tid == 0) {
    float p0=pS[0], p1=pS[1], p2=pS[2], p3=pS[3], p4=pS[4], p5=pS[5], p6=pS[6];
    float gainv = softplusf(p0) + 0.001f;
    float offv  = p1;
    float woffv = 0.05f * tanhf(p2);
    float wscv  = 1.0f + 0.005f * tanhf(p3);
    float lsf   = fminf(fmaxf(softplusf(p4) + 0.001f, 0.2f), 5.0f);
    float strv  = fminf(fmaxf((1.0f/(1.0f+expf(-p5))) * 0.05f, 0.0f), 0.2f);
    float nlin  = fminf(fmaxf(0.02f * tanhf(p6), -0.04f), 0.04f);
    float iw = 1.0f/(lsf + 1e-6f);
    float ks[15]; float ksum = 0.f;
    #pragma unroll
    for (int k2=0;k2<15;++k2){ float pp=(float)(k2-7)*iw; float e=expf(-0.5f*pp*pp); ks[k2]=e; ksum+=e; }
    float inv = 1.0f/ksum;
    scalS[15] = wscv;
    scalS[16] = (300.0f*(wscv - 1.0f) + woffv) * (8191.0f/100.0f);
    scalS[17] = gainv; scalS[18] = offv; scalS[19] = nlin; scalS[20] = strv;
    scalS[22] = air[row];
    unsigned* su = (unsigned*)scalS;
    #pragma unroll
    for (int i=0;i<7;++i) su[32+i] = pk2(ks[2*i]*inv, ks[2*i+1]*inv);
    su[39] = pk2(ks[14]*inv, 0.0f);
    su[40] = pk2(0.0f, ks[14]*inv);
    #pragma unroll
    for (int g=0; g<8; ++g) scalS[23+g] = gas[(size_t)row*8+g];
  }
  __syncthreads();

  const int wid = tid >> 6, l = tid & 63;
  const int segbase = wid * 2048;
  const unsigned* scalU = (const unsigned*)scalS;
  unsigned kwp[7];
  #pragma unroll
  for (int i=0;i<7;++i) kwp[i] = rflv(scalU[32+i]);
  const unsigned k14lo = rflv(scalU[39]), k14hi = rflv(scalU[40]);
  const float wscale = scalS[15], posoff = scalS[16];
  const float gainv  = scalS[17], offv   = scalS[18];
  const float nlin   = scalS[19], strv   = scalS[20];

  u16_t* ring = &ringS[wid][0];
  unsigned* ringU = (unsigned*)ring;
  u16_t* irow = &irowS2[wid][0];
  unsigned* irowU = (unsigned*)irow;

  auto do_diff = [&](int s){
    const int sbase = segbase - 256 + (s << 9);
    #pragma unroll
    for (int it=0; it<4; ++it){
      const int e0 = sbase + ((it*64 + l) << 1);
      const int eL = min(max(e0, 0), W_-2);
      const float am = scalS[22];
      float a0=0.f, a1=0.f;
      #pragma unroll
      for (int g=0; g<8; ++g){
        const float cg = scalS[23+g];
        const float ca = cg*am;
        a0 = fmaf(ca, absn[g*W_+eL],   a0); a0 = fmaf(cg, cbn[g*W_+eL],   a0);
        a1 = fmaf(ca, absn[g*W_+eL+1], a1); a1 = fmaf(cg, cbn[g*W_+eL+1], a1);
      }
      a0 += cbn[8*W_+eL]   + am*ray[eL];
      a1 += cbn[8*W_+eL+1] + am*ray[eL+1];
      ringU[((unsigned)e0 & 2047) >> 1] = pkrtz(a0, a1);
    }
  };

  float accsum = 0.f;
  unsigned nlp[4][4];

  do_diff(0); do_diff(1);
  __builtin_amdgcn_wave_barrier();

  #pragma unroll
  for (int c = 0; c < 4; ++c) {
    if (c < 3) do_diff(c+2);
    __builtin_amdgcn_wave_barrier();
    {
      const int cbase = segbase + (c << 9) - 8;
      #pragma unroll
      for (int it = 0; it < 5; ++it) {
        const int pi = it*64 + l;
        if (pi < 264) {
          float v2[2];
          #pragma unroll
          for (int u=0; u<2; ++u){
            const int j = cbase + 2*pi + u;
            const int jc = min(max(j, 0), W_-1);
            float pos = fmaf((float)jc, wscale, posoff);
            pos = fminf(fmaxf(pos, 0.0f), 8191.0f);
            const int i0 = min((int)pos, W_-2);
            const float fr = pos - (float)i0;
            const float d0 = h2f(ring[ i0    & 2047]);
            const float d1 = h2f(ring[(i0+1) & 2047]);
            v2[u] = fmaf(fr, d1-d0, d0);
          }
          irowU[pi] = pkrtz(v2[0], v2[1]);
        }
      }
    }
    __builtin_amdgcn_wave_barrier();
    {
      const uint4* qp = (const uint4*)irow + l;
      const uint4 A = qp[0], B = qp[1], C = qp[2];
      unsigned q[12] = {A.x,A.y,A.z,A.w, B.x,B.y,B.z,B.w, C.x,C.y,C.z,C.w};
      unsigned sh[10];
      #pragma unroll
      for (int m=0;m<10;++m) sh[m] = alignb(q[m+1], q[m]);
      float nlv[8];
      #pragma unroll
      for (int t=0;t<8;++t){
        const int s2 = t >> 1;
        float cv = 0.f;
        if ((t & 1) == 0){
          #pragma unroll
          for (int i=0;i<7;++i) cv = dot2u(sh[s2+i], kwp[i], cv);
          cv = dot2u(q[s2+7], k14hi, cv);
        } else {
          #pragma unroll
          for (int i=0;i<7;++i) cv = dot2u(q[s2+1+i], kwp[i], cv);
          cv = dot2u(q[s2+8], k14lo, cv);
        }
        const float counts = __expf(-cv);
        const float post = fmaf(gainv, counts, offv);
        const float v = fmaf(nlin*post, post, post);
        accsum += v;
        nlv[t] = v;
      }
      nlp[c][0] = pkrtz(nlv[0], nlv[1]);
      nlp[c][1] = pkrtz(nlv[2], nlv[3]);
      nlp[c][2] = pkrtz(nlv[4], nlv[5]);
      nlp[c][3] = pkrtz(nlv[6], nlv[7]);
    }
    __builtin_amdgcn_wave_barrier();
  }

  float s = accsum;
  #pragma unroll
  for (int off2 = 32; off2 >= 1; off2 >>= 1) s += __shfl_down(s, off2);
  if (l == 0) wsumS[wid] = s;
  __syncthreads();
  const float meanv = (wsumS[0]+wsumS[1]+wsumS[2]+wsumS[3]) * (1.0f/8192.0f);

  {
    const float aa = 1.0f - strv;
    const float bb = strv * meanv;
    float* orow = out + (size_t)row * W_;
    #pragma unroll
    for (int c = 0; c < 4; ++c) {
      const unsigned u0 = nlp[c][0], u1 = nlp[c][1], u2 = nlp[c][2], u3 = nlp[c][3];
      float4 o0, o1;
      o0.x = fmaf(aa, h2f((u16_t)(u0 & 0xffffu)), bb);
      o0.y = fmaf(aa, h2f((u16_t)(u0 >> 16)),     bb);
      o0.z = fmaf(aa, h2f((u16_t)(u1 & 0xffffu)), bb);
      o0.w = fmaf(aa, h2f((u16_t)(u1 >> 16)),     bb);
      o1.x = fmaf(aa, h2f((u16_t)(u2 & 0xffffu)), bb);
      o1.y = fmaf(aa, h2f((u16_t)(u2 >> 16)),     bb);
      o1.z = fmaf(aa, h2f((u16_t)(u3 & 0xffffu)), bb);
      o1.w = fmaf(aa, h2f((u16_t)(u3 >> 16)),     bb);
      float* dst = orow + segbase + (c << 9) + 8*l;
      *(float4*)(dst)     = o0;
      *(float4*)(dst + 4) = o1;
    }
  }
}

extern "C" void kernel_launch(void* const* d_in, const int* in_sizes, int n_in,
                              void* d_out, int out_size, void* d_ws, size_t ws_size,
                              hipStream_t stream) {
  const float* gas  = (const float*)d_in[0];
  const int*   iid  = (const int*)d_in[1];
  const float* nuis = (const float*)d_in[2];
  const float* air  = (const float*)d_in[3];
  const float* wl   = (const float*)d_in[4];
  const float* absn = (const float*)d_in[5];
  const float* cbn  = (const float*)d_in[6];
  const float* ray  = (const float*)d_in[7];
  const float* emb  = (const float*)d_in[8];
  const float* w1   = (const float*)d_in[9];
  const float* b1   = (const float*)d_in[10];
  const float* w2   = (const float*)d_in[11];
  const float* b2   = (const float*)d_in[12];
  float* out = (float*)d_out;
  (void)in_sizes; (void)n_in; (void)out_size; (void)wl;

  const size_t packBytes = (size_t)9 * W_ * 4;            // 288 KB
  const size_t parBytes  = (size_t)NBATCH * 16 * 4;       // 128 KB

  if (ws_size >= packBytes + parBytes) {
    unsigned* Tp  = (unsigned*)d_ws;
    float* params = (float*)((char*)d_ws + packBytes);
    hipLaunchKernelGGL(doas_prep, dim3(NBATCH/4), dim3(256), 0, stream,
                       absn, cbn, ray, iid, nuis, emb, w1, b1, w2, b2, Tp, params);
    hipLaunchKernelGGL(doas_main6, dim3(NBATCH), dim3(NT), 0, stream,
                       Tp, gas, air, params, out);
  } else {
    hipLaunchKernelGGL(doas_mono, dim3(NBATCH), dim3(256), 0, stream,
                       gas, iid, nuis, air, absn, cbn, ray, emb, w1, b1, w2, b2, out);
  }
}

// Round 15
// 51.556 us; speedup vs baseline: 1.2779x; 1.2779x over previous
//
#include <hip/hip_runtime.h>

#define W_ 8192
#define NBATCH 2048
#define NT 256
#define NWAVE 4
#define SEGW 2048
#define CCH 256
#define NCHW 8
#define IRW 272

typedef unsigned short u16_t;
typedef _Float16 h2v __attribute__((ext_vector_type(2)));

__device__ __forceinline__ u16_t f2h(float x){ _Float16 h=(_Float16)x; return __builtin_bit_cast(u16_t,h); }
__device__ __forceinline__ float h2f(u16_t u){ return (float)__builtin_bit_cast(_Float16,u); }
__device__ __forceinline__ unsigned pk2(float a,float b){ return (unsigned)f2h(a)|((unsigned)f2h(b)<<16); }
__device__ __forceinline__ float dot2u(unsigned a,unsigned b,float c){
#if __has_builtin(__builtin_amdgcn_fdot2)
  return __builtin_amdgcn_fdot2(__builtin_bit_cast(h2v,a),__builtin_bit_cast(h2v,b),c,false);
#else
  h2v ha=__builtin_bit_cast(h2v,a), hb=__builtin_bit_cast(h2v,b);
  return c+(float)ha[0]*(float)hb[0]+(float)ha[1]*(float)hb[1];
#endif
}
__device__ __forceinline__ unsigned pkrtz(float a,float b){
#if __has_builtin(__builtin_amdgcn_cvt_pkrtz)
  return __builtin_bit_cast(unsigned, __builtin_amdgcn_cvt_pkrtz(a,b));
#else
  return pk2(a,b);
#endif
}
__device__ __forceinline__ unsigned alignb(unsigned hi, unsigned lo){
#if __has_builtin(__builtin_amdgcn_alignbit)
  return __builtin_amdgcn_alignbit(hi, lo, 16);
#else
  return (lo >> 16) | (hi << 16);
#endif
}
__device__ __forceinline__ float softplusf(float x){ return fmaxf(x,0.f)+log1pf(expf(-fabsf(x))); }
__device__ __forceinline__ unsigned rflv(unsigned v){
  return (unsigned)__builtin_amdgcn_readfirstlane((int)v);
}
__device__ __forceinline__ float rflvf(float v){
  return __builtin_bit_cast(float, __builtin_amdgcn_readfirstlane(__builtin_bit_cast(int, v)));
}

// ---------------- K0: table pack + per-row params ----------------
__global__ __launch_bounds__(256, 2)
void doas_prep(const float* __restrict__ absn, const float* __restrict__ cbn,
               const float* __restrict__ ray, const int* __restrict__ iid,
               const float* __restrict__ nuis, const float* __restrict__ emb,
               const float* __restrict__ w1, const float* __restrict__ b1,
               const float* __restrict__ w2, const float* __restrict__ b2,
               unsigned* __restrict__ Tp, float* __restrict__ params){
  const int tid = threadIdx.x;
  const int b = blockIdx.x;
  __shared__ float hS[4][64];
  __shared__ float pS[4][8];

  if (b < 32){
    const int w = b*256 + tid;
    #pragma unroll
    for (int q=0;q<4;++q) Tp[q*W_+w]     = pk2(absn[(2*q)*W_+w], absn[(2*q+1)*W_+w]);
    #pragma unroll
    for (int q=0;q<4;++q) Tp[(4+q)*W_+w] = pk2(cbn[(2*q)*W_+w],  cbn[(2*q+1)*W_+w]);
    Tp[8*W_+w] = pk2(cbn[8*W_+w], ray[w]);
  }

  {
    const int rl = tid >> 6, j = tid & 63;
    const int r = b*4 + rl;
    const int id = iid[r];
    float acc = b1[j];
    const float* nrow = nuis + (size_t)r * 8;
    #pragma unroll
    for (int i = 0; i < 8; ++i) acc = fmaf(nrow[i], w1[i*64 + j], acc);
    const float* erow = emb + (size_t)id * 128;
    for (int i = 0; i < 128; ++i) acc = fmaf(erow[i], w1[(8+i)*64 + j], acc);
    hS[rl][j] = 0.5f * acc * (1.0f + erff(acc * 0.70710678118654752f));
  }
  __syncthreads();
  if (tid < 4*7){
    const int rl = tid / 7, k = tid % 7;
    float p = b2[k];
    for (int j = 0; j < 64; ++j) p = fmaf(hS[rl][j], w2[j*7+k], p);
    pS[rl][k] = p;
  }
  __syncthreads();
  if (tid < 4){
    const int rl = tid;
    const int r = b*4 + rl;
    float p0=pS[rl][0], p1=pS[rl][1], p2=pS[rl][2], p3=pS[rl][3],
          p4=pS[rl][4], p5=pS[rl][5], p6=pS[rl][6];
    float gainv = softplusf(p0) + 0.001f;
    float offv  = p1;
    float woffv = 0.05f * tanhf(p2);
    float wscv  = 1.0f + 0.005f * tanhf(p3);
    float lsf   = fminf(fmaxf(softplusf(p4) + 0.001f, 0.2f), 5.0f);
    float strv  = fminf(fmaxf((1.0f/(1.0f+expf(-p5))) * 0.05f, 0.0f), 0.2f);
    float nlin  = fminf(fmaxf(0.02f * tanhf(p6), -0.04f), 0.04f);
    float iw = 1.0f/(lsf + 1e-6f);
    float ks[15]; float ksum = 0.f;
    #pragma unroll
    for (int k2=0;k2<15;++k2){ float pp=(float)(k2-7)*iw; float e=expf(-0.5f*pp*pp); ks[k2]=e; ksum+=e; }
    float inv = 1.0f/ksum;
    float* pr = params + (size_t)r*16;
    unsigned* pu = (unsigned*)pr;
    #pragma unroll
    for (int i=0;i<7;++i) pu[i] = pk2(ks[2*i]*inv, ks[2*i+1]*inv);
    pu[7] = pk2(ks[14]*inv, 0.0f);   // k14lo
    pr[9]  = wscv;
    pr[10] = (300.0f*(wscv - 1.0f) + woffv) * (8191.0f/100.0f);  // posoff
    pr[11] = gainv; pr[12] = offv; pr[13] = nlin; pr[14] = strv;
    pr[15] = 0.f;
  }
}

// interp one 270-sample chunk (136 pairs) from full-row f16 LDS into wave irow
template<bool CLO, bool CHI>
__device__ __forceinline__ void interp_chunk(int cbase, int l, const unsigned* __restrict__ rU,
                                             unsigned* __restrict__ irowU,
                                             float wscale, float posoff){
  #pragma unroll
  for (int it=0; it<3; ++it){
    const int pi = it*64 + l;
    if (pi < 136){
      float v2[2];
      #pragma unroll
      for (int u=0;u<2;++u){
        int j = cbase + 2*pi + u;
        if (CLO) j = max(j, 0);
        if (CHI) j = min(j, W_-1);
        float pos = fmaf((float)j, wscale, posoff);
        if (CLO) pos = fmaxf(pos, 0.0f);
        if (CHI) pos = fminf(pos, 8191.0f);
        int i0 = (int)pos;
        if (CHI) i0 = min(i0, W_-2);
        const float fr = pos - (float)i0;
        const int m = i0 >> 1;
        const unsigned u0 = rU[m];
        const unsigned u1 = rU[m+1];
        const unsigned hu0 = u0 >> 16;
        const bool odd = (i0 & 1);
        const unsigned ua = odd ? hu0 : u0;
        const unsigned ub = odd ? u1  : hu0;
        const float d0 = h2f((u16_t)ua);
        const float d1 = h2f((u16_t)ub);
        v2[u] = fmaf(fr, d1-d0, d0);
      }
      irowU[pi] = pkrtz(v2[0], v2[1]);
    }
  }
}

// ---------------- K1: fused diff+interp+conv+post; 1 row/block, 4 waves ----------------
__global__ __launch_bounds__(NT, 2)
void doas_main7(const unsigned* __restrict__ Tp, const float* __restrict__ gas,
                const float* __restrict__ air, const float* __restrict__ params,
                float* __restrict__ out){
  __shared__ u16_t rowH[W_ + 16];        // 16.4 KB full f16 diff row (+pad)
  __shared__ u16_t irowS[NWAVE][IRW];    // 2.2 KB
  __shared__ float wsumS[NWAVE];

  const int tid = threadIdx.x;
  const int row = blockIdx.x;
  const int wid = tid >> 6, l = tid & 63;
  const int segbase = wid * SEGW;

  // ---- diff coefficients (row-uniform) -> SGPRs ----
  unsigned csg[9];
  {
    const float am = air[row];
    const float* gfp = gas + (size_t)row * 8;
    #pragma unroll
    for (int q=0;q<4;++q) csg[q]   = rflv(pk2(gfp[2*q]*am, gfp[2*q+1]*am));
    #pragma unroll
    for (int q=0;q<4;++q) csg[4+q] = rflv(pk2(gfp[2*q],    gfp[2*q+1]));
    csg[8] = rflv(pk2(1.0f, am));
  }

  // ---- per-row params (wave-uniform) ----
  const float* pr = params + (size_t)row * 16;
  const unsigned* pu = (const unsigned*)pr;
  unsigned kwp[7];
  #pragma unroll
  for (int i=0;i<7;++i) kwp[i] = rflv(pu[i]);
  const unsigned k14lo = rflv(pu[7]);
  const float wscale = rflvf(pr[9]),  posoff = rflvf(pr[10]);
  const float gainv  = rflvf(pr[11]), offv   = rflvf(pr[12]);
  const float nlin   = rflvf(pr[13]), strv   = rflvf(pr[14]);

  // ---- stage: whole row diff into LDS (uint4 table loads, 4 elems/thread/iter) ----
  unsigned* rowHU = (unsigned*)rowH;
  #pragma unroll
  for (int it=0; it<8; ++it){
    const int e0 = it*1024 + tid*4;
    uint4 dq[9];
    #pragma unroll
    for (int q=0;q<9;++q) dq[q] = *(const uint4*)(Tp + q*W_ + e0);
    float a0=0.f, a1=0.f, a2=0.f, a3=0.f;
    #pragma unroll
    for (int q=0;q<9;++q){
      a0 = dot2u(dq[q].x, csg[q], a0);
      a1 = dot2u(dq[q].y, csg[q], a1);
      a2 = dot2u(dq[q].z, csg[q], a2);
      a3 = dot2u(dq[q].w, csg[q], a3);
    }
    *(uint2*)(rowHU + (e0 >> 1)) = make_uint2(pkrtz(a0,a1), pkrtz(a2,a3));
  }
  __syncthreads();   // rowH ready (only block-wide sync before mean)

  const unsigned* rU = (const unsigned*)rowH;
  u16_t* irow = &irowS[wid][0];
  unsigned* irowU = (unsigned*)irow;

  float accsum = 0.f;
  unsigned nlp[NCHW][2];

  #pragma unroll
  for (int c = 0; c < NCHW; ++c) {
    const int cs = segbase + c*CCH;
    const int cbase = cs - 8;
    if (wid == 0 && c == 0)
      interp_chunk<true,false>(cbase, l, rU, irowU, wscale, posoff);
    else if (wid == NWAVE-1 && c == NCHW-1)
      interp_chunk<false,true>(cbase, l, rU, irowU, wscale, posoff);
    else
      interp_chunk<false,false>(cbase, l, rU, irowU, wscale, posoff);
    __builtin_amdgcn_wave_barrier();
    // conv(15) + exp + post + nl ; lane owns 4 outputs at cs + 4l
    {
      const uint2* p2 = (const uint2*)irowU + l;
      const uint2 A = p2[0], B = p2[1], C = p2[2], D = p2[3], E = p2[4];
      unsigned q[10] = {A.x,A.y, B.x,B.y, C.x,C.y, D.x,D.y, E.x,E.y};
      unsigned sh[9];
      #pragma unroll
      for (int m=0;m<9;++m) sh[m] = alignb(q[m+1], q[m]);
      float nlv[4];
      #pragma unroll
      for (int t=0;t<4;++t){
        float cv = 0.f;
        if ((t & 1) == 0){
          const int b0 = t >> 1;
          #pragma unroll
          for (int i=0;i<7;++i) cv = dot2u(sh[b0+i], kwp[i], cv);
          cv = dot2u(sh[b0+7], k14lo, cv);
        } else {
          const int b0 = (t+1) >> 1;
          #pragma unroll
          for (int i=0;i<7;++i) cv = dot2u(q[b0+i], kwp[i], cv);
          cv = dot2u(q[b0+7], k14lo, cv);
        }
        const float counts = __expf(-cv);
        const float post = fmaf(gainv, counts, offv);
        const float v = fmaf(nlin*post, post, post);
        accsum += v;
        nlv[t] = v;
      }
      nlp[c][0] = pkrtz(nlv[0], nlv[1]);
      nlp[c][1] = pkrtz(nlv[2], nlv[3]);
    }
    __builtin_amdgcn_wave_barrier();
  }

  // ---- row mean ----
  float s = accsum;
  #pragma unroll
  for (int off2 = 32; off2 >= 1; off2 >>= 1) s += __shfl_down(s, off2);
  if (l == 0) wsumS[wid] = s;
  __syncthreads();
  const float meanv = (wsumS[0]+wsumS[1]+wsumS[2]+wsumS[3]) * (1.0f/8192.0f);

  // ---- final write ----
  {
    const float aa = 1.0f - strv;
    const float bb = strv * meanv;
    float* orow = out + (size_t)row * W_;
    #pragma unroll
    for (int c = 0; c < NCHW; ++c) {
      const unsigned u0 = nlp[c][0], u1 = nlp[c][1];
      float4 o0;
      o0.x = fmaf(aa, h2f((u16_t)(u0 & 0xffffu)), bb);
      o0.y = fmaf(aa, h2f((u16_t)(u0 >> 16)),     bb);
      o0.z = fmaf(aa, h2f((u16_t)(u1 & 0xffffu)), bb);
      o0.w = fmaf(aa, h2f((u16_t)(u1 >> 16)),     bb);
      *(float4*)(orow + segbase + c*CCH + 4*l) = o0;
    }
  }
}

// ---------------- fallback: monolithic kernel reading raw tables ----------------
__global__ __launch_bounds__(256, 2)
void doas_mono(const float* __restrict__ gas, const int* __restrict__ iid,
               const float* __restrict__ nuis, const float* __restrict__ air,
               const float* __restrict__ absn, const float* __restrict__ cbn,
               const float* __restrict__ ray, const float* __restrict__ emb,
               const float* __restrict__ w1, const float* __restrict__ b1,
               const float* __restrict__ w2, const float* __restrict__ b2,
               float* __restrict__ out)
{
  __shared__ u16_t ringS[4][2048];
  __shared__ u16_t irowS2[4][544];
  __shared__ float hS[64];
  __shared__ float pS[8];
  __shared__ float scalS[52];
  __shared__ float wsumS[4];

  const int tid = threadIdx.x;
  const int row = blockIdx.x;

  if (tid < 64) {
    const int j = tid;
    const int id = iid[row];
    float acc = b1[j];
    const float* nrow = nuis + (size_t)row * 8;
    #pragma unroll
    for (int i = 0; i < 8; ++i) acc = fmaf(nrow[i], w1[i*64 + j], acc);
    const float* erow = emb + (size_t)id * 128;
    for (int i = 0; i < 128; ++i) acc = fmaf(erow[i], w1[(8+i)*64 + j], acc);
    hS[j] = 0.5f * acc * (1.0f + erff(acc * 0.70710678118654752f));
  }
  __syncthreads();
  if (tid < 7) {
    float p = b2[tid];
    for (int j = 0; j < 64; ++j) p = fmaf(hS[j], w2[j*7+tid], p);
    pS[tid] = p;
  }
  __syncthreads();
  if (tid == 0) {
    float p0=pS[0], p1=pS[1], p2=pS[2], p3=pS[3], p4=pS[4], p5=pS[5], p6=pS[6];
    float gainv = softplusf(p0) + 0.001f;
    float offv  = p1;
    float woffv = 0.05f * tanhf(p2);
    float wscv  = 1.0f + 0.005f * tanhf(p3);
    float lsf   = fminf(fmaxf(softplusf(p4) + 0.001f, 0.2f), 5.0f);
    float strv  = fminf(fmaxf((1.0f/(1.0f+expf(-p5))) * 0.05f, 0.0f), 0.2f);
    float nlin  = fminf(fmaxf(0.02f * tanhf(p6), -0.04f), 0.04f);
    float iw = 1.0f/(lsf + 1e-6f);
    float ks[15]; float ksum = 0.f;
    #pragma unroll
    for (int k2=0;k2<15;++k2){ float pp=(float)(k2-7)*iw; float e=expf(-0.5f*pp*pp); ks[k2]=e; ksum+=e; }
    float inv = 1.0f/ksum;
    scalS[15] = wscv;
    scalS[16] = (300.0f*(wscv - 1.0f) + woffv) * (8191.0f/100.0f);
    scalS[17] = gainv; scalS[18] = offv; scalS[19] = nlin; scalS[20] = strv;
    scalS[22] = air[row];
    unsigned* su = (unsigned*)scalS;
    #pragma unroll
    for (int i=0;i<7;++i) su[32+i] = pk2(ks[2*i]*inv, ks[2*i+1]*inv);
    su[39] = pk2(ks[14]*inv, 0.0f);
    su[40] = pk2(0.0f, ks[14]*inv);
    #pragma unroll
    for (int g=0; g<8; ++g) scalS[23+g] = gas[(size_t)row*8+g];
  }
  __syncthreads();

  const int wid = tid >> 6, l = tid & 63;
  const int segbase = wid * 2048;
  const unsigned* scalU = (const unsigned*)scalS;
  unsigned kwp[7];
  #pragma unroll
  for (int i=0;i<7;++i) kwp[i] = rflv(scalU[32+i]);
  const unsigned k14lo = rflv(scalU[39]), k14hi = rflv(scalU[40]);
  const float wscale = scalS[15], posoff = scalS[16];
  const float gainv  = scalS[17], offv   = scalS[18];
  const float nlin   = scalS[19], strv   = scalS[20];

  u16_t* ring = &ringS[wid][0];
  unsigned* ringU = (unsigned*)ring;
  u16_t* irow = &irowS2[wid][0];
  unsigned* irowU = (unsigned*)irow;

  auto do_diff = [&](int s){
    const int sbase = segbase - 256 + (s << 9);
    #pragma unroll
    for (int it=0; it<4; ++it){
      const int e0 = sbase + ((it*64 + l) << 1);
      const int eL = min(max(e0, 0), W_-2);
      const float am = scalS[22];
      float a0=0.f, a1=0.f;
      #pragma unroll
      for (int g=0; g<8; ++g){
        const float cg = scalS[23+g];
        const float ca = cg*am;
        a0 = fmaf(ca, absn[g*W_+eL],   a0); a0 = fmaf(cg, cbn[g*W_+eL],   a0);
        a1 = fmaf(ca, absn[g*W_+eL+1], a1); a1 = fmaf(cg, cbn[g*W_+eL+1], a1);
      }
      a0 += cbn[8*W_+eL]   + am*ray[eL];
      a1 += cbn[8*W_+eL+1] + am*ray[eL+1];
      ringU[((unsigned)e0 & 2047) >> 1] = pkrtz(a0, a1);
    }
  };

  float accsum = 0.f;
  unsigned nlp[4][4];

  do_diff(0); do_diff(1);
  __builtin_amdgcn_wave_barrier();

  #pragma unroll
  for (int c = 0; c < 4; ++c) {
    if (c < 3) do_diff(c+2);
    __builtin_amdgcn_wave_barrier();
    {
      const int cbase = segbase + (c << 9) - 8;
      #pragma unroll
      for (int it = 0; it < 5; ++it) {
        const int pi = it*64 + l;
        if (pi < 264) {
          float v2[2];
          #pragma unroll
          for (int u=0; u<2; ++u){
            const int j = cbase + 2*pi + u;
            const int jc = min(max(j, 0), W_-1);
            float pos = fmaf((float)jc, wscale, posoff);
            pos = fminf(fmaxf(pos, 0.0f), 8191.0f);
            const int i0 = min((int)pos, W_-2);
            const float fr = pos - (float)i0;
            const float d0 = h2f(ring[ i0    & 2047]);
            const float d1 = h2f(ring[(i0+1) & 2047]);
            v2[u] = fmaf(fr, d1-d0, d0);
          }
          irowU[pi] = pkrtz(v2[0], v2[1]);
        }
      }
    }
    __builtin_amdgcn_wave_barrier();
    {
      const uint4* qp = (const uint4*)irow + l;
      const uint4 A = qp[0], B = qp[1], C = qp[2];
      unsigned q[12] = {A.x,A.y,A.z,A.w, B.x,B.y,B.z,B.w, C.x,C.y,C.z,C.w};
      unsigned sh[10];
      #pragma unroll
      for (int m=0;m<10;++m) sh[m] = alignb(q[m+1], q[m]);
      float nlv[8];
      #pragma unroll
      for (int t=0;t<8;++t){
        const int s2 = t >> 1;
        float cv = 0.f;
        if ((t & 1) == 0){
          #pragma unroll
          for (int i=0;i<7;++i) cv = dot2u(sh[s2+i], kwp[i], cv);
          cv = dot2u(q[s2+7], k14hi, cv);
        } else {
          #pragma unroll
          for (int i=0;i<7;++i) cv = dot2u(q[s2+1+i], kwp[i], cv);
          cv = dot2u(q[s2+8], k14lo, cv);
        }
        const float counts = __expf(-cv);
        const float post = fmaf(gainv, counts, offv);
        const float v = fmaf(nlin*post, post, post);
        accsum += v;
        nlv[t] = v;
      }
      nlp[c][0] = pkrtz(nlv[0], nlv[1]);
      nlp[c][1] = pkrtz(nlv[2], nlv[3]);
      nlp[c][2] = pkrtz(nlv[4], nlv[5]);
      nlp[c][3] = pkrtz(nlv[6], nlv[7]);
    }
    __builtin_amdgcn_wave_barrier();
  }

  float s = accsum;
  #pragma unroll
  for (int off2 = 32; off2 >= 1; off2 >>= 1) s += __shfl_down(s, off2);
  if (l == 0) wsumS[wid] = s;
  __syncthreads();
  const float meanv = (wsumS[0]+wsumS[1]+wsumS[2]+wsumS[3]) * (1.0f/8192.0f);

  {
    const float aa = 1.0f - strv;
    const float bb = strv * meanv;
    float* orow = out + (size_t)row * W_;
    #pragma unroll
    for (int c = 0; c < 4; ++c) {
      const unsigned u0 = nlp[c][0], u1 = nlp[c][1], u2 = nlp[c][2], u3 = nlp[c][3];
      float4 o0, o1;
      o0.x = fmaf(aa, h2f((u16_t)(u0 & 0xffffu)), bb);
      o0.y = fmaf(aa, h2f((u16_t)(u0 >> 16)),     bb);
      o0.z = fmaf(aa, h2f((u16_t)(u1 & 0xffffu)), bb);
      o0.w = fmaf(aa, h2f((u16_t)(u1 >> 16)),     bb);
      o1.x = fmaf(aa, h2f((u16_t)(u2 & 0xffffu)), bb);
      o1.y = fmaf(aa, h2f((u16_t)(u2 >> 16)),     bb);
      o1.z = fmaf(aa, h2f((u16_t)(u3 & 0xffffu)), bb);
      o1.w = fmaf(aa, h2f((u16_t)(u3 >> 16)),     bb);
      float* dst = orow + segbase + (c << 9) + 8*l;
      *(float4*)(dst)     = o0;
      *(float4*)(dst + 4) = o1;
    }
  }
}

extern "C" void kernel_launch(void* const* d_in, const int* in_sizes, int n_in,
                              void* d_out, int out_size, void* d_ws, size_t ws_size,
                              hipStream_t stream) {
  const float* gas  = (const float*)d_in[0];
  const int*   iid  = (const int*)d_in[1];
  const float* nuis = (const float*)d_in[2];
  const float* air  = (const float*)d_in[3];
  const float* wl   = (const float*)d_in[4];
  const float* absn = (const float*)d_in[5];
  const float* cbn  = (const float*)d_in[6];
  const float* ray  = (const float*)d_in[7];
  const float* emb  = (const float*)d_in[8];
  const float* w1   = (const float*)d_in[9];
  const float* b1   = (const float*)d_in[10];
  const float* w2   = (const float*)d_in[11];
  const float* b2   = (const float*)d_in[12];
  float* out = (float*)d_out;
  (void)in_sizes; (void)n_in; (void)out_size; (void)wl;

  const size_t packBytes = (size_t)9 * W_ * 4;            // 288 KB
  const size_t parBytes  = (size_t)NBATCH * 16 * 4;       // 128 KB

  if (ws_size >= packBytes + parBytes) {
    unsigned* Tp  = (unsigned*)d_ws;
    float* params = (float*)((char*)d_ws + packBytes);
    hipLaunchKernelGGL(doas_prep, dim3(NBATCH/4), dim3(256), 0, stream,
                       absn, cbn, ray, iid, nuis, emb, w1, b1, w2, b2, Tp, params);
    hipLaunchKernelGGL(doas_main7, dim3(NBATCH), dim3(NT), 0, stream,
                       Tp, gas, air, params, out);
  } else {
    hipLaunchKernelGGL(doas_mono, dim3(NBATCH), dim3(256), 0, stream,
                       gas, iid, nuis, air, absn, cbn, ray, emb, w1, b1, w2, b2, out);
  }
}